// Round 3
// baseline (1079.460 us; speedup 1.0000x reference)
//
#include <hip/hip_runtime.h>

#define EMB_DIM 64
#define SCAN_T 256
#define SCAN_E 8
#define SCAN_CHUNK (SCAN_T * SCAN_E)   // 2048

// ---------- init: acc = x = concat(user, item) ----------
__global__ void lgcn_init(const float* __restrict__ user_w,
                          const float* __restrict__ item_w,
                          float* __restrict__ acc,
                          float* __restrict__ x,
                          int user_n4, int n4) {
    int i = blockIdx.x * blockDim.x + threadIdx.x;
    if (i >= n4) return;
    float4 v;
    if (i < user_n4) v = ((const float4*)user_w)[i];
    else             v = ((const float4*)item_w)[i - user_n4];
    ((float4*)acc)[i] = v;
    ((float4*)x)[i]   = v;
}

// ---------- CSR build ----------
__global__ void k_zero(int* __restrict__ p, int n) {
    int i = blockIdx.x * blockDim.x + threadIdx.x;
    if (i < n) p[i] = 0;
}

// 4 edges per thread via int4 load
__global__ void k_hist(const int* __restrict__ erow, int* __restrict__ counts, int nnz) {
    int i = blockIdx.x * blockDim.x + threadIdx.x;
    int base = i * 4;
    if (base + 4 <= nnz) {
        int4 r = ((const int4*)erow)[i];
        atomicAdd(&counts[r.x], 1);
        atomicAdd(&counts[r.y], 1);
        atomicAdd(&counts[r.z], 1);
        atomicAdd(&counts[r.w], 1);
    } else {
        for (int k = base; k < nnz; ++k) atomicAdd(&counts[erow[k]], 1);
    }
}

// pass1: per-block sums of counts
__global__ void k_scan1(const int* __restrict__ counts, int* __restrict__ bsum, int n) {
    __shared__ int s[SCAN_T];
    int base = blockIdx.x * SCAN_CHUNK;
    int t = threadIdx.x;
    int acc = 0;
    for (int k = 0; k < SCAN_E; ++k) {
        int idx = base + t * SCAN_E + k;
        if (idx < n) acc += counts[idx];
    }
    s[t] = acc;
    __syncthreads();
    for (int d = SCAN_T / 2; d > 0; d >>= 1) {
        if (t < d) s[t] += s[t + d];
        __syncthreads();
    }
    if (t == 0) bsum[blockIdx.x] = s[0];
}

// pass2: serial exclusive scan of block sums (nb ~ 74, trivial)
__global__ void k_scan2(const int* __restrict__ bsum, int* __restrict__ bscan, int nb) {
    if (threadIdx.x == 0 && blockIdx.x == 0) {
        int run = 0;
        for (int i = 0; i < nb; ++i) { bscan[i] = run; run += bsum[i]; }
    }
}

// pass3: block-local exclusive scan + block offset -> row_ptr, cursor
__global__ void k_scan3(const int* __restrict__ counts,
                        const int* __restrict__ bscan,
                        int* __restrict__ row_ptr,
                        int* __restrict__ cursor, int n) {
    __shared__ int s[SCAN_T];
    int base = blockIdx.x * SCAN_CHUNK;
    int t = threadIdx.x;
    int v[SCAN_E];
    int tot = 0;
    for (int k = 0; k < SCAN_E; ++k) {
        int idx = base + t * SCAN_E + k;
        v[k] = (idx < n) ? counts[idx] : 0;
        tot += v[k];
    }
    s[t] = tot;
    __syncthreads();
    for (int d = 1; d < SCAN_T; d <<= 1) {
        int add = (t >= d) ? s[t - d] : 0;
        __syncthreads();
        s[t] += add;
        __syncthreads();
    }
    int off = bscan[blockIdx.x] + s[t] - tot;  // exclusive prefix for this thread
    for (int k = 0; k < SCAN_E; ++k) {
        int idx = base + t * SCAN_E + k;
        if (idx < n) { row_ptr[idx] = off; cursor[idx] = off; }
        off += v[k];
    }
}

// scatter packed (col, val) as one 8B store
__global__ void k_scatter(const int* __restrict__ erow,
                          const int* __restrict__ ecol,
                          const float* __restrict__ eval_,
                          int* __restrict__ cursor,
                          int2* __restrict__ edges, int nnz) {
    int i = blockIdx.x * blockDim.x + threadIdx.x;
    if (i >= nnz) return;
    int r = erow[i];
    int c = ecol[i];
    float v = eval_[i];
    int pos = atomicAdd(&cursor[r], 1);
    edges[pos] = make_int2(c, __float_as_int(v));
}

// ---------- CSR SpMM: one wave per row, lane = dim; fused layer-accumulate ----------
__global__ void lgcn_spmm_csr(const int* __restrict__ row_ptr,
                              const int* __restrict__ row_end,
                              const int2* __restrict__ edges,
                              const float* __restrict__ x,
                              float* __restrict__ y,
                              float* __restrict__ out,
                              float scale, int is_last, int n) {
    int w = (blockIdx.x * blockDim.x + threadIdx.x) >> 6;
    int lane = threadIdx.x & 63;
    if (w >= n) return;
    int start = row_ptr[w];
    int end   = row_end[w];
    float acc = 0.f;
    int j = start;
    for (; j + 4 <= end; j += 4) {
        int2 e0 = edges[j],     e1 = edges[j + 1];
        int2 e2 = edges[j + 2], e3 = edges[j + 3];
        float x0 = x[(size_t)e0.x * EMB_DIM + lane];
        float x1 = x[(size_t)e1.x * EMB_DIM + lane];
        float x2 = x[(size_t)e2.x * EMB_DIM + lane];
        float x3 = x[(size_t)e3.x * EMB_DIM + lane];
        acc += __int_as_float(e0.y) * x0 + __int_as_float(e1.y) * x1
             + __int_as_float(e2.y) * x2 + __int_as_float(e3.y) * x3;
    }
    for (; j < end; ++j) {
        int2 e = edges[j];
        acc += __int_as_float(e.y) * x[(size_t)e.x * EMB_DIM + lane];
    }
    size_t oi = (size_t)w * EMB_DIM + lane;
    y[oi] = acc;
    float a = out[oi] + acc;
    out[oi] = is_last ? a * scale : a;
}

extern "C" void kernel_launch(void* const* d_in, const int* in_sizes, int n_in,
                              void* d_out, int out_size, void* d_ws, size_t ws_size,
                              hipStream_t stream) {
    const float* user_w = (const float*)d_in[0];
    const float* item_w = (const float*)d_in[1];
    const int*   erow   = (const int*)d_in[2];
    const int*   ecol   = (const int*)d_in[3];
    const float* eval_  = (const float*)d_in[4];

    int n_users = in_sizes[0] / EMB_DIM;
    int n_items = in_sizes[1] / EMB_DIM;
    int n_total = n_users + n_items;
    int nnz     = in_sizes[2];

    // workspace layout
    char* ws = (char*)d_ws;
    float* x      = (float*)ws;                 ws += (size_t)n_total * EMB_DIM * 4;
    float* y      = (float*)ws;                 ws += (size_t)n_total * EMB_DIM * 4;
    int2*  edges  = (int2*)ws;                  ws += (size_t)nnz * 8;
    int*   counts = (int*)ws;                   ws += (size_t)n_total * 4;
    int*   row_ptr= (int*)ws;                   ws += (size_t)n_total * 4;
    int*   cursor = (int*)ws;                   ws += (size_t)n_total * 4;
    int*   bsum   = (int*)ws;                   ws += 4096;
    int*   bscan  = (int*)ws;                   ws += 4096;

    float* acc = (float*)d_out;
    int n4      = n_total * EMB_DIM / 4;
    int user_n4 = n_users * EMB_DIM / 4;

    lgcn_init<<<(n4 + 255) / 256, 256, 0, stream>>>(user_w, item_w, acc, x, user_n4, n4);

    // CSR build
    int nb = (n_total + SCAN_CHUNK - 1) / SCAN_CHUNK;
    k_zero<<<(n_total + 255) / 256, 256, 0, stream>>>(counts, n_total);
    int histT = (nnz + 3) / 4;
    k_hist<<<(histT + 255) / 256, 256, 0, stream>>>(erow, counts, nnz);
    k_scan1<<<nb, SCAN_T, 0, stream>>>(counts, bsum, n_total);
    k_scan2<<<1, 64, 0, stream>>>(bsum, bscan, nb);
    k_scan3<<<nb, SCAN_T, 0, stream>>>(counts, bscan, row_ptr, cursor, n_total);
    k_scatter<<<(nnz + 255) / 256, 256, 0, stream>>>(erow, ecol, eval_, cursor, edges, nnz);
    // after scatter, cursor[r] == row end

    // 3 propagation layers, ping-pong x/y, accumulate into d_out
    float* xin = x;
    float* yout = y;
    int waves_per_block = 256 / 64;
    int blocks = (n_total + waves_per_block - 1) / waves_per_block;
    for (int layer = 0; layer < 3; ++layer) {
        const bool last = (layer == 2);
        lgcn_spmm_csr<<<blocks, 256, 0, stream>>>(
            row_ptr, cursor, edges, xin, yout, acc,
            0.25f, last ? 1 : 0, n_total);
        float* t = xin; xin = yout; yout = t;
    }
}